// Round 5
// baseline (102.623 us; speedup 1.0000x reference)
//
#include <hip/hip_runtime.h>

#define N_SAMP 16384
#define N_CENT 4096
#define DIM    128
#define LAMBD  1.0f
#define NSLOT  256

typedef _Float16 half8  __attribute__((ext_vector_type(8)));
typedef float    floatx4 __attribute__((ext_vector_type(4)));

// One accumulation slot per 128-B cache line; blocks sharing a slot share
// (bid % 8) so slot lines don't ping-pong across XCDs under round-robin.
struct Slot { float sum; unsigned int cnt; unsigned int pad[30]; };

__device__ __forceinline__ void gload_lds16(const void* g, void* l) {
  __builtin_amdgcn_global_load_lds(
      (__attribute__((address_space(1))) void*)(g),
      (__attribute__((address_space(3))) void*)(l), 16, 0, 0);
}

// ---------------------------------------------------------------------------
// Fused prep (single launch):
//   blocks [0, 5120): one wave per row -- rowk[i] = lambd + sum c*(c-2e) over
//     center y_i (waves 0..N_SAMP) or c2[c] = ||c||^2 (waves N_SAMP..+N_CENT).
//     Block 0 additionally zeroes the 256 accumulation slots.
//   blocks [5120, 6400): f32->f16 convert of E then C, 16B->8B per thread.
// ---------------------------------------------------------------------------
__global__ __launch_bounds__(256) void prep_kernel(
    const float* __restrict__ E, const float* __restrict__ Cc,
    const int* __restrict__ tgt,
    _Float16* __restrict__ Eh, _Float16* __restrict__ Ch,
    float* __restrict__ c2, float* __restrict__ rowk,
    Slot* __restrict__ slots) {
  const int tid = threadIdx.x;
  const int STAT_BLOCKS = (N_SAMP + N_CENT) / 4;  // 5120
  if ((int)blockIdx.x < STAT_BLOCKS) {
    if (blockIdx.x == 0) { slots[tid].sum = 0.f; slots[tid].cnt = 0u; }
    const int wv   = blockIdx.x * 4 + (tid >> 6);
    const int lane = tid & 63;
    if (wv < N_SAMP) {
      const int yi = tgt[wv];
      float2 e = *(const float2*)(E  + (size_t)wv * DIM + lane * 2);
      float2 c = *(const float2*)(Cc + (size_t)yi * DIM + lane * 2);
      float s = c.x * (c.x - 2.f * e.x) + c.y * (c.y - 2.f * e.y);
      #pragma unroll
      for (int off = 32; off > 0; off >>= 1) s += __shfl_down(s, off);
      if (lane == 0) rowk[wv] = LAMBD + s;
    } else {
      const int cI = wv - N_SAMP;
      float2 c = *(const float2*)(Cc + (size_t)cI * DIM + lane * 2);
      float s = c.x * c.x + c.y * c.y;
      #pragma unroll
      for (int off = 32; off > 0; off >>= 1) s += __shfl_down(s, off);
      if (lane == 0) c2[cI] = s;
    }
  } else {
    const int t = ((int)blockIdx.x - STAT_BLOCKS) * 256 + tid;
    const int NE8 = N_SAMP * DIM / 8;   // 262144
    const float4* src;
    half8* dst;
    int idx;
    if (t < NE8) { src = (const float4*)E;  dst = (half8*)Eh; idx = t; }
    else         { src = (const float4*)Cc; dst = (half8*)Ch; idx = t - NE8; }
    float4 a = src[(size_t)idx * 2], b = src[(size_t)idx * 2 + 1];
    half8 h;
    h[0]=(_Float16)a.x; h[1]=(_Float16)a.y; h[2]=(_Float16)a.z; h[3]=(_Float16)a.w;
    h[4]=(_Float16)b.x; h[5]=(_Float16)b.y; h[6]=(_Float16)b.z; h[7]=(_Float16)b.w;
    dst[idx] = h;
  }
}

// ---------------------------------------------------------------------------
// Main GEMM: 256x256 output tile per block, 512 threads (8 waves, 4x2), K=128
// one-shot. Each wave computes 64x128 via 4x8 MFMAs (acc = 32 floatx4).
// XOR-swizzled LDS staging via global_load_lds (0 bank conflicts), bucketed
// slot atomics. 131 KB LDS -> 1 block/CU; launch_bounds caps VGPR at 256.
// vs round 4: total staged bytes 256 MB -> 128 MB, 4x MFMA per staged byte.
// ---------------------------------------------------------------------------
__global__ __launch_bounds__(512, 1) void center_gemm_kernel(
    const _Float16* __restrict__ Eh, const _Float16* __restrict__ Ch,
    const float* __restrict__ c2, const float* __restrict__ rowk,
    const int* __restrict__ tgt,
    Slot* __restrict__ slots) {
  __shared__ _Float16 As[256 * DIM];   // 64 KB
  __shared__ _Float16 Bs[256 * DIM];   // 64 KB
  __shared__ float rowkS[256];
  __shared__ float c2S[256];
  __shared__ int   yS[256];
  __shared__ float swsum[8];
  __shared__ int   swcnt[8];

  const int tid  = threadIdx.x;
  const int w    = tid >> 6;          // 0..7
  const int lane = tid & 63;

  // XCD-grouped mapping (kept from round 4; harmless if mapping guess wrong).
  const int bid = blockIdx.x;          // 0..1023
  const int xcd = bid & 7;
  const int j   = bid >> 3;            // 0..127
  const int bm  = xcd * 8 + (j & 7);   // 0..63  (256-row tiles)
  const int bn  = j >> 3;              // 0..15  (256-col tiles)

  {
    const char* gA = (const char*)(Eh + (size_t)bm * 256 * DIM);
    const char* gB = (const char*)(Ch + (size_t)bn * 256 * DIM);
    char* lA = (char*)As;
    char* lB = (char*)Bs;
    const int p  = lane & 15;
    const int r4 = lane >> 4;
    #pragma unroll
    for (int it = 0; it < 8; ++it) {
      const int off = (w * 8 + it) * 1024;        // 0..64512
      const int row = (w * 8 + it) * 4 + r4;      // 0..255
      const int gof = row * 256 + (p ^ (row & 15)) * 16;
      gload_lds16(gA + gof, lA + off);
      gload_lds16(gB + gof, lB + off);
    }
  }
  if (tid < 256) {
    rowkS[tid] = rowk[bm * 256 + tid];
    yS[tid]    = tgt[bm * 256 + tid];
    c2S[tid]   = c2[bn * 256 + tid];
  }
  __syncthreads();

  const int wm = w >> 1, wn = w & 1;
  const int q = lane >> 4, r = lane & 15;
  const int row0 = wm * 64, col0 = wn * 128;

  floatx4 acc[4][8];
  #pragma unroll
  for (int a = 0; a < 4; ++a)
    #pragma unroll
    for (int b = 0; b < 8; ++b)
      acc[a][b] = (floatx4){0.f, 0.f, 0.f, 0.f};

  #pragma unroll
  for (int ks = 0; ks < 4; ++ks) {
    const int cidx = ks * 4 + q;
    half8 af[4], bf[8];
    #pragma unroll
    for (int mt = 0; mt < 4; ++mt)
      af[mt] = *(const half8*)&As[(row0 + mt * 16 + r) * DIM + ((cidx ^ r) * 8)];
    #pragma unroll
    for (int nt = 0; nt < 8; ++nt)
      bf[nt] = *(const half8*)&Bs[(col0 + nt * 16 + r) * DIM + ((cidx ^ r) * 8)];
    #pragma unroll
    for (int mt = 0; mt < 4; ++mt)
      #pragma unroll
      for (int nt = 0; nt < 8; ++nt)
        acc[mt][nt] = __builtin_amdgcn_mfma_f32_16x16x32_f16(af[mt], bf[nt], acc[mt][nt], 0, 0, 0);
  }

  float lsum = 0.f;
  int   lcnt = 0;
  #pragma unroll
  for (int mt = 0; mt < 4; ++mt) {
    float rk[4]; int yv[4];
    #pragma unroll
    for (int rg = 0; rg < 4; ++rg) {
      const int row = row0 + mt * 16 + q * 4 + rg;
      rk[rg] = rowkS[row];
      yv[rg] = yS[row];
    }
    #pragma unroll
    for (int nt = 0; nt < 8; ++nt) {
      const int col  = col0 + nt * 16 + r;
      const float c2v = c2S[col];
      const int gcol = bn * 256 + col;
      #pragma unroll
      for (int rg = 0; rg < 4; ++rg) {
        const float v = rk[rg] + 2.f * acc[mt][nt][rg] - c2v;
        const bool mined = (v > 0.f) & (gcol != yv[rg]);
        lsum += mined ? v : 0.f;
        lcnt += mined ? 1 : 0;
      }
    }
  }

  #pragma unroll
  for (int off = 32; off > 0; off >>= 1) {
    lsum += __shfl_down(lsum, off);
    lcnt += __shfl_down(lcnt, off);
  }
  if (lane == 0) { swsum[w] = lsum; swcnt[w] = lcnt; }
  __syncthreads();
  if (tid == 0) {
    float s = 0.f; int c = 0;
    #pragma unroll
    for (int k = 0; k < 8; ++k) { s += swsum[k]; c += swcnt[k]; }
    Slot* sl = &slots[bid & (NSLOT - 1)];
    atomicAdd(&sl->sum, s);
    atomicAdd(&sl->cnt, (unsigned int)c);
  }
}

__global__ __launch_bounds__(256) void finalize_kernel(
    const Slot* __restrict__ slots, float* __restrict__ out) {
  const int tid = threadIdx.x;
  float s = slots[tid].sum;
  unsigned int c = slots[tid].cnt;
  #pragma unroll
  for (int off = 32; off > 0; off >>= 1) {
    s += __shfl_down(s, off);
    c += __shfl_down(c, off);
  }
  __shared__ float ss[4];
  __shared__ unsigned int sc[4];
  if ((tid & 63) == 0) { ss[tid >> 6] = s; sc[tid >> 6] = c; }
  __syncthreads();
  if (tid == 0) {
    const float S = ss[0] + ss[1] + ss[2] + ss[3];
    const unsigned int C = sc[0] + sc[1] + sc[2] + sc[3];
    out[0] = (C > 0u) ? (S / (float)C) : 0.f;
  }
}

// ---------------------------------------------------------------------------
// Fallback (tiny ws): fp32 vector path, one block per sample.
// ---------------------------------------------------------------------------
__global__ void zero_kernel(float* ws_sum, unsigned int* ws_cnt) {
  if (threadIdx.x == 0) { *ws_sum = 0.f; *ws_cnt = 0u; }
}

__global__ void finalize_simple(const float* __restrict__ ws_sum,
                                const unsigned int* __restrict__ ws_cnt,
                                float* __restrict__ out) {
  if (threadIdx.x == 0 && blockIdx.x == 0) {
    const unsigned int c = *ws_cnt;
    out[0] = (c > 0u) ? (*ws_sum / (float)c) : 0.f;
  }
}

__global__ __launch_bounds__(256) void fallback_kernel(
    const float* __restrict__ E, const float* __restrict__ Cc,
    const int* __restrict__ tgt,
    float* __restrict__ ws_sum, unsigned int* __restrict__ ws_cnt) {
  __shared__ float eS[DIM];
  __shared__ float apS;
  const int i = blockIdx.x;
  const int tid = threadIdx.x;
  if (tid < DIM) eS[tid] = E[(size_t)i * DIM + tid];
  __syncthreads();
  const int yi = tgt[i];
  float dloc[16];
  #pragma unroll
  for (int j = 0; j < 16; ++j) {
    const int c = tid + 256 * j;
    const float* cp = Cc + (size_t)c * DIM;
    float s = 0.f;
    for (int d = 0; d < DIM; d += 4) {
      float4 cv = *(const float4*)(cp + d);
      s += cv.x * (cv.x - 2.f * eS[d + 0]) + cv.y * (cv.y - 2.f * eS[d + 1])
         + cv.z * (cv.z - 2.f * eS[d + 2]) + cv.w * (cv.w - 2.f * eS[d + 3]);
    }
    dloc[j] = s;
    if (c == yi) apS = s;
  }
  __syncthreads();
  const float apv = apS;
  float lsum = 0.f; int lcnt = 0;
  #pragma unroll
  for (int j = 0; j < 16; ++j) {
    const int c = tid + 256 * j;
    const float v = LAMBD + apv - dloc[j];
    const bool mined = (v > 0.f) & (c != yi);
    lsum += mined ? v : 0.f;
    lcnt += mined ? 1 : 0;
  }
  #pragma unroll
  for (int off = 32; off > 0; off >>= 1) {
    lsum += __shfl_down(lsum, off);
    lcnt += __shfl_down(lcnt, off);
  }
  __shared__ float swsum[4];
  __shared__ int   swcnt[4];
  const int w = tid >> 6, lane = tid & 63;
  if (lane == 0) { swsum[w] = lsum; swcnt[w] = lcnt; }
  __syncthreads();
  if (tid == 0) {
    atomicAdd(ws_sum, swsum[0] + swsum[1] + swsum[2] + swsum[3]);
    atomicAdd(ws_cnt, (unsigned int)(swcnt[0] + swcnt[1] + swcnt[2] + swcnt[3]));
  }
}

extern "C" void kernel_launch(void* const* d_in, const int* in_sizes, int n_in,
                              void* d_out, int out_size, void* d_ws, size_t ws_size,
                              hipStream_t stream) {
  const float* E   = (const float*)d_in[0];
  const int*   tgt = (const int*)d_in[1];
  const float* Cc  = (const float*)d_in[2];
  float* out = (float*)d_out;

  const size_t EH_BYTES = (size_t)N_SAMP * DIM * 2;   // 4 MB
  const size_t CH_BYTES = (size_t)N_CENT * DIM * 2;   // 1 MB
  const size_t C2_BYTES = (size_t)N_CENT * 4;         // 16 KB
  const size_t RK_BYTES = (size_t)N_SAMP * 4;         // 64 KB
  const size_t SL_BYTES = (size_t)NSLOT * sizeof(Slot); // 32 KB
  const size_t NEEDED = EH_BYTES + CH_BYTES + C2_BYTES + RK_BYTES + SL_BYTES;

  char* ws = (char*)d_ws;
  if (ws_size >= NEEDED) {
    _Float16* Eh = (_Float16*)ws;
    _Float16* Ch = (_Float16*)(ws + EH_BYTES);
    float* c2    = (float*)(ws + EH_BYTES + CH_BYTES);
    float* rowk  = (float*)(ws + EH_BYTES + CH_BYTES + C2_BYTES);
    Slot* slots  = (Slot*)(ws + EH_BYTES + CH_BYTES + C2_BYTES + RK_BYTES);

    const int STAT_BLOCKS = (N_SAMP + N_CENT) / 4;                        // 5120
    const int CONV_BLOCKS = (N_SAMP * DIM / 8 + N_CENT * DIM / 8) / 256;  // 1280
    prep_kernel<<<STAT_BLOCKS + CONV_BLOCKS, 256, 0, stream>>>(
        E, Cc, tgt, Eh, Ch, c2, rowk, slots);
    center_gemm_kernel<<<(N_CENT / 256) * (N_SAMP / 256), 512, 0, stream>>>(
        Eh, Ch, c2, rowk, tgt, slots);
    finalize_kernel<<<1, 256, 0, stream>>>(slots, out);
  } else {
    float* ws_sum = (float*)ws;
    unsigned int* ws_cnt = (unsigned int*)(ws_sum + 1);
    zero_kernel<<<1, 64, 0, stream>>>(ws_sum, ws_cnt);
    fallback_kernel<<<N_SAMP, 256, 0, stream>>>(E, Cc, tgt, ws_sum, ws_cnt);
    finalize_simple<<<1, 64, 0, stream>>>(ws_sum, ws_cnt, out);
  }
}